// Round 9
// baseline (334.224 us; speedup 1.0000x reference)
//
#include <hip/hip_runtime.h>
#include <hip/hip_cooperative_groups.h>
#include <hip/hip_bf16.h>
#include <float.h>

namespace cg = cooperative_groups;

#define N_PATCH 216
#define DIM 125
#define HEADS 8
#define HEAD_DIM 64
#define QK 512           // HEADS*HEAD_DIM
#define NH (HEADS*N_PATCH)   // 1728

// ws layout (floats):
//  q    : [216][512]   off 0       (110592)
//  k    : [216][512]   off 110592  (110592)
//  stats: [16][2]      off 221184  (32)   raw sums {S,SS}; idx=(isK*8+h)
//  Qt   : [8][64][216] off 221216  (110592)
//  Kn   : [8][216][64] off 331808  (110592)
//  x4   : [72][72][72] off 442400  (373248)
//  t1   : [20][72][72] off 815648  (103680)

// Single cooperative kernel, 432 blocks x 256 threads, 2 blocks/CU co-resident.
// Phases separated by grid.sync(). All latency hidden by TLP (compiler won't
// pipeline: VGPR=12 across R4/R6/R7 attempts).
__global__ __launch_bounds__(256, 2) void k_mega(
        const float* __restrict__ x,  const float* __restrict__ Wq,
        const float* __restrict__ Wk, const float* __restrict__ bnw,
        const float* __restrict__ bnb,const float* __restrict__ W1,
        const float* __restrict__ W2, const float* __restrict__ W3,
        float* __restrict__ qg, float* __restrict__ kg, float* __restrict__ stats,
        float* __restrict__ Qt, float* __restrict__ Kn, float* __restrict__ x4,
        float* __restrict__ t1, float* __restrict__ att, float* __restrict__ out0) {
    cg::grid_group grid = cg::this_grid();
    __shared__ float lds[7168];          // 28 KB, reused per phase
    __shared__ float rs[4], rss[4];
    const int bid = blockIdx.x, t = threadIdx.x;
    const int wv = t >> 6, lane = t & 63;

    // ---- P1: projection q,k = x @ {Wq,Wk}^T, fused BN-stat sums ----
    // 288 active blocks: 32 col-groups x 9 patch-groups(24). W rows contiguous
    // from ORIGINAL layout (no transpose). Wl bank = (col*29+i)%32: conflict-free.
    if (bid < 288) {
        const int cgp = bid & 31, pg = bid >> 5;
        const int isK = cgp >> 4, c0 = (cgp & 15) * 32, p0 = pg * 24;
        const float* Wsrc = isK ? Wk : Wq;
        float* dst = isK ? kg : qg;
        float* Wl = lds;                 // [32*125]
        float* xp = lds + 4000;          // [24*125]
        for (int idx = t; idx < 32*DIM; idx += 256) Wl[idx] = Wsrc[c0*DIM + idx];
        for (int idx = t; idx < 24*DIM; idx += 256) xp[idx] = x[p0*DIM + idx];
        __syncthreads();
        const int col = t & 31, pl = t >> 5;     // 32 cols x 8 patch-lanes x 3
        float a0 = 0.f, a1 = 0.f, a2 = 0.f;
        #pragma unroll 5
        for (int i = 0; i < DIM; ++i) {
            float w = Wl[col*DIM + i];           // 32 distinct banks
            a0 = fmaf(xp[ pl     *DIM + i], w, a0);  // broadcast in 32-group
            a1 = fmaf(xp[(pl+ 8)*DIM + i], w, a1);
            a2 = fmaf(xp[(pl+16)*DIM + i], w, a2);
        }
        dst[(p0+pl   )*QK + c0 + col] = a0;
        dst[(p0+pl+ 8)*QK + c0 + col] = a1;
        dst[(p0+pl+16)*QK + c0 + col] = a2;
        float s = a0+a1+a2, ss = a0*a0+a1*a1+a2*a2;
        #pragma unroll
        for (int off = 32; off; off >>= 1) {
            s  += __shfl_down(s,  off, 64);
            ss += __shfl_down(ss, off, 64);
        }
        if (lane == 0) { rs[wv] = s; rss[wv] = ss; }
        __syncthreads();
        if (t == 0) {
            float S  = rs[0]+rs[1]+rs[2]+rs[3];
            float SS = rss[0]+rss[1]+rss[2]+rss[3];
            int h = c0 >> 6;
            atomicAdd(&stats[(isK*8+h)*2],   S);
            atomicAdd(&stats[(isK*8+h)*2+1], SS);
        }
    }
    grid.sync();

    // ---- P2: BN (batch stats) + L2-normalize -> Qt (transposed), Kn ----
    for (int gw = bid*4 + wv; gw < 2*NH; gw += 1728) {
        int isK = (gw >= NH) ? 1 : 0;
        int r = isK ? gw - NH : gw;
        int h = r / N_PATCH, n = r % N_PATCH;
        const float* src = isK ? kg : qg;
        int sb = (isK*8 + h)*2;
        const float invN = 1.0f/13824.0f;
        float mean = stats[sb]*invN;
        float var  = stats[sb+1]*invN - mean*mean;
        float inv = 1.0f / sqrtf(var + 1e-5f);
        float w = bnw[h], b = bnb[h];
        float v = src[n*QK + h*HEAD_DIM + lane];
        float xh = (v - mean)*inv*w + b;
        float sq = xh*xh;
        #pragma unroll
        for (int off = 32; off; off >>= 1) sq += __shfl_xor(sq, off, 64);
        float nrm = fmaxf(sqrtf(sq), 1e-12f);
        float o = xh / nrm;
        if (isK) Kn[(h*N_PATCH + n)*HEAD_DIM + lane] = o;
        else     Qt[h*HEAD_DIM*N_PATCH + lane*N_PATCH + n] = o;
    }
    grid.sync();

    // ---- P3: scores + sort-free sparsemax (Newton on tau), 1 col/wave ----
    {
        const int c = bid*4 + wv;            // exactly 0..1727
        const int h = c / N_PATCH, m = c % N_PATCH;
        float* ks = lds;                     // [4][64]
        ks[wv*HEAD_DIM + lane] = Kn[(h*N_PATCH+m)*HEAD_DIM + lane];
        __syncthreads();
        const float* qh = Qt + h*HEAD_DIM*N_PATCH;
        float z0=0.f, z1=0.f, z2=0.f, z3=0.f;
        const bool v3 = (lane < N_PATCH - 192);  // lane<24
        #pragma unroll 8
        for (int d = 0; d < HEAD_DIM; ++d) {
            float kd = ks[wv*HEAD_DIM + d];
            z0 = fmaf(qh[d*N_PATCH + lane],       kd, z0);
            z1 = fmaf(qh[d*N_PATCH + 64 + lane],  kd, z1);
            z2 = fmaf(qh[d*N_PATCH + 128 + lane], kd, z2);
            if (v3) z3 = fmaf(qh[d*N_PATCH + 192 + lane], kd, z3);
        }
        const float scale = 0.08944271909999159f;   // 1/sqrt(125)
        z0 *= scale; z1 *= scale; z2 *= scale; z3 *= scale;
        float mx = fmaxf(fmaxf(z0, z1), fmaxf(z2, v3 ? z3 : -FLT_MAX));
        #pragma unroll
        for (int off = 32; off; off >>= 1) mx = fmaxf(mx, __shfl_xor(mx, off, 64));
        float tau = mx - 1.0f;               // g(tau0) >= 0
        for (int it = 0; it < 20; ++it) {
            float g = fmaxf(z0-tau,0.f) + fmaxf(z1-tau,0.f) + fmaxf(z2-tau,0.f)
                    + (v3 ? fmaxf(z3-tau,0.f) : 0.f);
            float cnt = (z0>tau ? 1.f:0.f) + (z1>tau ? 1.f:0.f) + (z2>tau ? 1.f:0.f)
                      + ((v3 && z3>tau) ? 1.f:0.f);
            #pragma unroll
            for (int off = 32; off; off >>= 1) {
                g   += __shfl_xor(g,   off, 64);
                cnt += __shfl_xor(cnt, off, 64);
            }
            g -= 1.0f;
            if (g <= 1e-6f) break;           // wave-uniform
            tau += g / cnt;                  // Newton (monotone from left)
        }
        #pragma unroll
        for (int j = 0; j < 4; ++j) {
            int n = lane + 64*j;
            if (n >= N_PATCH) break;
            float zz = (j==0) ? z0 : (j==1) ? z1 : (j==2) ? z2 : z3;
            float a = fmaxf(zz - tau, 0.f);
            att[n*NH + c] = a;
            // permute (2,2,2,6,6,6,6,6,6) axes (0,3,6,1,4,7,2,5,8) -> [72,72,72]
            int nh2 = n / 27;
            int d0 = nh2 >> 2, d1 = (nh2 >> 1) & 1, d2 = nh2 & 1;
            int r = (n % 27)*NH + c;
            int d3 = r / 7776; r -= d3*7776;
            int d4 = r / 1296; r -= d4*1296;
            int d5 = r / 216;  r -= d5*216;
            int d6 = r / 36;   r -= d6*36;
            int d7 = r / 6;
            int d8 = r - d7*6;
            int ii  = d0*36 + d3*6 + d6;
            int jj  = d1*36 + d4*6 + d7;
            int kk2 = d2*36 + d5*6 + d8;
            x4[(ii*72 + jj)*72 + kk2] = a;
        }
    }
    grid.sync();

    // ---- P4: TCL mode-1: t1[a,jk] = sum_i W1[a,i] x4[i,jk] ----
    {
        int o = bid*256 + t;                 // 110592 threads >= 103680 outputs
        if (o < 103680) {
            int a = o / 5184, jk = o % 5184;
            float acc = 0.f;
            #pragma unroll 8
            for (int i = 0; i < 72; ++i) acc += W1[a*72+i]*x4[i*5184 + jk];
            t1[o] = acc;
        }
    }
    grid.sync();

    // ---- P5: TCL modes 2+3 fused + tanh; blocks 0..19 (one per a) ----
    if (bid < 20) {
        float* t1a = lds;                    // [5184]
        float* t2a = lds + 5184;             // [1440]
        const int a = bid;
        __syncthreads();                     // lds reuse guard within block
        for (int i = t; i < 5184; i += 256) t1a[i] = t1[a*5184 + i];
        __syncthreads();
        for (int idx = t; idx < 1440; idx += 256) {
            int cc = idx / 72, kk = idx % 72;
            float acc = 0.f;
            #pragma unroll 8
            for (int j = 0; j < 72; ++j) acc += W2[cc*72+j]*t1a[j*72 + kk];
            t2a[idx] = acc;
        }
        __syncthreads();
        for (int idx = t; idx < 400; idx += 256) {
            int cc = idx / 20, dd = idx % 20;
            float acc = 0.f;
            #pragma unroll 8
            for (int kq = 0; kq < 72; ++kq) acc += W3[dd*72+kq]*t2a[cc*72 + kq];
            out0[(a*20 + cc)*20 + dd] = tanhf(acc);
        }
    }
}

extern "C" void kernel_launch(void* const* d_in, const int* in_sizes, int n_in,
                              void* d_out, int out_size, void* d_ws, size_t ws_size,
                              hipStream_t stream) {
    const float* patches = (const float*)d_in[0];
    const float* Wq = (const float*)d_in[1];
    const float* Wk = (const float*)d_in[2];
    const float* bnw = (const float*)d_in[3];
    const float* bnb = (const float*)d_in[4];
    const float* W1 = (const float*)d_in[5];
    const float* W2 = (const float*)d_in[6];
    const float* W3 = (const float*)d_in[7];
    float* out = (float*)d_out;
    float* ws = (float*)d_ws;

    float* qg    = ws;
    float* kg    = ws + 110592;
    float* stats = ws + 221184;
    float* Qt    = ws + 221216;
    float* Kn    = ws + 331808;
    float* x4    = ws + 442400;
    float* t1    = ws + 815648;

    float* out0 = out;          // tanh(x5): 8000 floats
    float* att  = out + 8000;   // att: 216*1728 floats

    hipMemsetAsync(stats, 0, 32*sizeof(float), stream);

    void* args[] = { (void*)&patches, (void*)&Wq, (void*)&Wk, (void*)&bnw,
                     (void*)&bnb, (void*)&W1, (void*)&W2, (void*)&W3,
                     (void*)&qg, (void*)&kg, (void*)&stats, (void*)&Qt,
                     (void*)&Kn, (void*)&x4, (void*)&t1, (void*)&att,
                     (void*)&out0 };
    hipLaunchCooperativeKernel((const void*)k_mega, dim3(432), dim3(256),
                               args, 0, stream);
}